// Round 12
// baseline (86.079 us; speedup 1.0000x reference)
//
#include <hip/hip_runtime.h>

#define NN 100000
#define DIN 128
#define DOUT 64
#define NE 1600000

// place granularity (proven): 128-row buckets
#define BSHIFT 7
#define BROWS 128
#define NBB 783              // ceil(100000/128)
#define NBP 1024             // padded key count for place scan
#define CAP 2560             // slots per 128-bucket; mean 2048 -> +11 sigma
#define EPB 4096             // edges per place-block
#define NBLK 391             // ceil(1600000/4096)

// agg granularity (proven): 64-row buckets, carved in-place from CAP/2
#define NB64 1566            // 2 * NBB
#define CAP64 1280           // CAP/2; mean 1024, sigma 32 -> +8 sigma
#define QRN64 5              // CAP64 / 256 (exact)
#define QRNS 10              // CAP / 256 (split reg cache, exact)

// ---------------- ws layout (bytes) ----------------
#define XWB_B   0u                           // ushort[NN*DOUT] = 12.8 MB
#define GCUR_B  12800000u                    // int[NBB]   (3.1 KB)
#define GCUR64_B (GCUR_B + 4096u)            // int[NB64]  (6.3 KB)
#define BPAD_B  (GCUR_B + 16384u)            // int2[NBB*CAP] = 16.04 MB
#define WS_NEED (BPAD_B + (unsigned)NBB * CAP * 8u)   // ~28.9 MB

typedef unsigned short u16;
typedef unsigned int u32;
typedef __attribute__((ext_vector_type(8))) short v8s;   // 8 bf16 = 4 VGPR
typedef __attribute__((ext_vector_type(4))) float v4f;   // MFMA acc

__device__ __forceinline__ float bf2f(u16 u) {
  return __uint_as_float(((u32)u) << 16);
}
__device__ __forceinline__ u16 f2bf(float f) {
  u32 x = __float_as_uint(f);
  u32 r = x + 0x7fffu + ((x >> 16) & 1u);
  return (u16)(r >> 16);
}

// ---------------------------------------------------------------------------
// GEMM v7 (validated, ~11 us, HBM-bound). Grid 1563 >= NBB=783: one block
// zeroes one gcur128 slot (gcur64 needs no zeroing -- split overwrites it).
// ---------------------------------------------------------------------------
__global__ __launch_bounds__(256) void gemm_kernel(
    const float* __restrict__ x, const float* __restrict__ w,
    u16* __restrict__ xwb, int* __restrict__ gz) {
  if (gz != nullptr && threadIdx.x == 0 && blockIdx.x < NBB)
    gz[blockIdx.x] = 0;

  __shared__ u16 wlds[16 * 64 * 8];   // 16 KB
  const int t = threadIdx.x;
  const int lane = t & 63;
  const int wv = t >> 6;

  #pragma unroll
  for (int pi = 0; pi < 4; ++pi) {
    const int p = t * 4 + pi;
    const int f = p >> 6, lp = p & 63;
    const int kc = f >> 2, nc = f & 3;
    const int kg = lp >> 4, lr = lp & 15;
    const int kbase = kc * 32 + kg * 8;
    u32 pk[4];
    #pragma unroll
    for (int h = 0; h < 4; ++h) {
      const u32 lo = f2bf(w[(kbase + 2 * h)     * DOUT + nc * 16 + lr]);
      const u32 hi = f2bf(w[(kbase + 2 * h + 1) * DOUT + nc * 16 + lr]);
      pk[h] = lo | (hi << 16);
    }
    *reinterpret_cast<uint4*>(&wlds[p * 8]) =
        make_uint4(pk[0], pk[1], pk[2], pk[3]);
  }
  __syncthreads();

  const int row0 = blockIdx.x * 64 + wv * 16;
  if (row0 >= NN) return;            // safe: after the only barrier
  const int lrow = lane & 15;
  const int lkg  = lane >> 4;

  v8s Bf[4][4];
  #pragma unroll
  for (int kc = 0; kc < 4; ++kc)
    #pragma unroll
    for (int nc = 0; nc < 4; ++nc)
      Bf[kc][nc] = *reinterpret_cast<const v8s*>(
          &wlds[((kc * 4 + nc) * 64 + lane) * 8]);

  const float* xr = x + (size_t)(row0 + lrow) * DIN + lkg * 8;
  float4 xa[4][2];
  #pragma unroll
  for (int kc = 0; kc < 4; ++kc) {
    xa[kc][0] = *reinterpret_cast<const float4*>(xr + kc * 32);
    xa[kc][1] = *reinterpret_cast<const float4*>(xr + kc * 32 + 4);
  }

  v4f acc[4];
  #pragma unroll
  for (int nc = 0; nc < 4; ++nc) acc[nc] = (v4f){0.f, 0.f, 0.f, 0.f};

  #pragma unroll
  for (int kc = 0; kc < 4; ++kc) {
    v8s Af;
    Af[0] = (short)f2bf(xa[kc][0].x);
    Af[1] = (short)f2bf(xa[kc][0].y);
    Af[2] = (short)f2bf(xa[kc][0].z);
    Af[3] = (short)f2bf(xa[kc][0].w);
    Af[4] = (short)f2bf(xa[kc][1].x);
    Af[5] = (short)f2bf(xa[kc][1].y);
    Af[6] = (short)f2bf(xa[kc][1].z);
    Af[7] = (short)f2bf(xa[kc][1].w);
    #pragma unroll
    for (int nc = 0; nc < 4; ++nc)
      acc[nc] = __builtin_amdgcn_mfma_f32_16x16x32_bf16(Af, Bf[kc][nc],
                                                        acc[nc], 0, 0, 0);
  }

  #pragma unroll
  for (int nc = 0; nc < 4; ++nc)
    #pragma unroll
    for (int j = 0; j < 4; ++j)
      xwb[(size_t)(row0 + lkg * 4 + j) * DOUT + nc * 16 + lrow] =
          f2bf(acc[nc][j]);
}

// ---------------------------------------------------------------------------
// place5 (proven ~21 us, verbatim): EPB=4096 / 512 thr / reg-cached edge
// loads / LDS counting sort / run-contiguous bpad writes, 128-row buckets
// (runs ~5.2 edges). base overlays hist in-place after the scan. LDS 52 KB.
// ---------------------------------------------------------------------------
__global__ __launch_bounds__(512) void place5_kernel(
    const int* __restrict__ erow, const int* __restrict__ ecol,
    const float* __restrict__ eval_, int* __restrict__ gcur,
    int2* __restrict__ bpad) {
  __shared__ int  hist[NBP];       // 4 KB (holds base[] after the claim)
  __shared__ int  lofs[NBP];       // 4 KB
  __shared__ int  lcur[NBP];       // 4 KB
  __shared__ int  wtot[8];
  __shared__ u16  sb[EPB];         // 8 KB   bucket id per sorted pos
  __shared__ int2 dstl[EPB];       // 32 KB  payload per sorted pos

  const int t = threadIdx.x;
  const int lane = t & 63;
  const int wv = t >> 6;
  const int e0 = blockIdx.x * EPB;
  const int e1 = min(e0 + EPB, NE);
  const int ecount = e1 - e0;

  hist[t] = 0;        hist[t + 512] = 0;
  lcur[t] = 0;        lcur[t + 512] = 0;
  __syncthreads();

  // A: histogram; cache all edge data in registers (independent loads)
  int er[8], ec[8];
  float ev[8];
  #pragma unroll
  for (int k = 0; k < 8; ++k) {
    const int e = e0 + t + k * 512;
    if (e < e1) {
      er[k] = erow[e];
      ec[k] = ecol[e];
      ev[k] = eval_[e];
      atomicAdd(&hist[er[k] >> BSHIFT], 1);
    } else {
      er[k] = -1;
    }
  }
  __syncthreads();

  // B: exclusive scan over 1024 keys (pair-per-thread + wave shfl + offsets)
  const int ha = hist[2 * t], hb = hist[2 * t + 1];
  const int ps = ha + hb;
  int s = ps;
  #pragma unroll
  for (int o = 1; o < 64; o <<= 1) {
    const int u = __shfl_up(s, o);
    if (lane >= o) s += u;
  }
  if (lane == 63) wtot[wv] = s;
  __syncthreads();
  int woff = 0;
  #pragma unroll
  for (int w8 = 0; w8 < 8; ++w8) woff += (w8 < wv) ? wtot[w8] : 0;
  const int excl = woff + s - ps;
  lofs[2 * t]     = excl;
  lofs[2 * t + 1] = excl + ha;
  // claim bucket ranges; base overlays hist (owner-thread slots, no race)
  hist[2 * t]     = (ha && 2 * t     < NBB) ? atomicAdd(&gcur[2 * t],     ha) : 0;
  hist[2 * t + 1] = (hb && 2 * t + 1 < NBB) ? atomicAdd(&gcur[2 * t + 1], hb) : 0;
  __syncthreads();

  // C: rank + scatter payload into LDS sorted order (pure LDS)
  #pragma unroll
  for (int k = 0; k < 8; ++k) {
    if (er[k] >= 0) {
      const int b = er[k] >> BSHIFT;
      const int pos = lofs[b] + atomicAdd(&lcur[b], 1);
      dstl[pos] = make_int2(((er[k] & (BROWS - 1)) << 17) | ec[k],
                            __float_as_int(ev[k]));
      sb[pos] = (u16)b;
    }
  }
  __syncthreads();

  // D: stream sorted payload to bpad (runs of ~5.2 edges = contiguous)
  for (int p = t; p < ecount; p += 512) {
    const int b = sb[p];
    const int rk = hist[b] + (p - lofs[b]);   // hist[] holds base now
    if (rk < CAP) bpad[(long)b * CAP + rk] = dstl[p];
  }
}

// ---------------------------------------------------------------------------
// split (round-25, NEW): in-place halving adapter between place's 128-row
// buckets and agg's 64-row buckets. Block b loads its whole 2560-slot
// segment into qr[10] (coalesced), barrier (vmcnt drained -> in-place
// safe), then ballot-partitions by q.x bit 23 (= row bit 6) with
// wave-aggregated LDS counters. CAP64 = CAP/2 so the two sub-segments
// land exactly inside the parent footprint: lo at [b*2560, +1280),
// hi at [+1280, +2560). Writes are per-wave coalesced runs. Emits exact
// gcur64 counts (no zeroing pass needed). Pure streaming, no global
// atomics, ~31 MB L2-friendly traffic.
// ---------------------------------------------------------------------------
__global__ __launch_bounds__(256) void split_kernel(
    const int* __restrict__ gcur, int2* __restrict__ bpad,
    int* __restrict__ gcur64) {
  __shared__ int cnt2[2];
  const int b = blockIdx.x;
  const int t = threadIdx.x;
  const int lane = t & 63;
  const int count = min(gcur[b], CAP);
  const long sbase = (long)b * CAP;

  if (t < 2) cnt2[t] = 0;
  __syncthreads();

  int2 qr[QRNS];
  #pragma unroll
  for (int k = 0; k < QRNS; ++k) {
    const int e = t + k * 256;
    qr[k] = (e < count) ? bpad[sbase + e] : make_int2(-1, 0);
  }
  __syncthreads();   // all segment reads drained before any in-place write

  #pragma unroll
  for (int k = 0; k < QRNS; ++k) {
    const bool valid = qr[k].x >= 0;          // real q.x < 2^24
    const int half = (qr[k].x >> 23) & 1;     // row bit 6
    const unsigned long long mlo = __ballot(valid && !half);
    const unsigned long long mhi = __ballot(valid && half);
    int bl = 0, bh = 0;
    if (lane == 0) {
      bl = atomicAdd(&cnt2[0], (int)__popcll(mlo));
      bh = atomicAdd(&cnt2[1], (int)__popcll(mhi));
    }
    bl = __shfl(bl, 0);
    bh = __shfl(bh, 0);
    if (valid) {
      const unsigned long long lm = (1ull << lane) - 1ull;
      const int pos = half ? bh + (int)__popcll(mhi & lm)
                           : bl + (int)__popcll(mlo & lm);
      if (pos < CAP64)
        bpad[sbase + (long)half * CAP64 + pos] = qr[k];
    }
  }
  __syncthreads();
  if (t == 0) gcur64[2 * b]     = min(cnt2[0], CAP64);
  if (t == 1) gcur64[2 * b + 1] = min(cnt2[1], CAP64);
}

// ---------------------------------------------------------------------------
// agg3 (PROVEN ~23 us shape, verbatim structure): one 256-thr block per
// 64-row bucket, grid 1566 (6264 waves -- the wave count the latency-bound
// gather loop needs). Segment reg-cached in qr[5] (CAP64 = 5*256 exact);
// hist/scan/sort; slot-vectorized loop: wave = 4 slots x 16 lanes, dwordx2
// gathers, val=0 tail masking, cross-slot shfl_xor reduce, float4 store.
// ---------------------------------------------------------------------------
__global__ __launch_bounds__(256) void agg3_kernel(
    const int* __restrict__ gcur64, const int2* __restrict__ bpad,
    const u16* __restrict__ xwb, float* __restrict__ out) {
  __shared__ int2 dst[CAP64];      // 10240 B
  __shared__ int  hist[64];
  __shared__ int  lptr[65];
  __shared__ int  cur[64];

  const int bucket = blockIdx.x;           // 64-row bucket id, 0..1565
  const int t = threadIdx.x;
  const int count = min(gcur64[bucket], CAP64);
  const long sbase = (long)bucket * CAP64; // = parent*CAP + half*CAP64

  if (t < 64) hist[t] = 0;
  __syncthreads();

  // single global read of this bucket's edges; cached in regs across phases
  int2 qr[QRN64];
  #pragma unroll
  for (int k = 0; k < QRN64; ++k) {
    const int e = t + k * 256;
    qr[k].x = -1;
    if (e < count) {
      qr[k] = bpad[sbase + e];
      atomicAdd(&hist[(qr[k].x >> 17) & 63], 1);
    }
  }
  __syncthreads();

  if (t < 64) {
    const int v = hist[t];
    int s = v;
    #pragma unroll
    for (int o = 1; o < 64; o <<= 1) {
      const int u = __shfl_up(s, o);
      if (t >= o) s += u;
    }
    lptr[t + 1] = s;
    cur[t] = s - v;
    if (t == 0) lptr[0] = 0;
  }
  __syncthreads();

  #pragma unroll
  for (int k = 0; k < QRN64; ++k) {
    if (qr[k].x >= 0) {
      const int r = (qr[k].x >> 17) & 63;
      const int pos = atomicAdd(&cur[r], 1);
      dst[pos] = qr[k];
    }
  }
  __syncthreads();

  const int lane = t & 63;
  const int wave = t >> 6;
  const int slot = lane >> 4;      // 0..3  (edge sub-slot)
  const int li   = lane & 15;      // 0..15 (covers 4 cols each via dwordx2)
  const int row0 = bucket << 6;
  const int cmax = count - 1;

  for (int r = wave; r < 64; r += 4) {
    const int row = row0 + r;
    if (row >= NN) break;
    const int s = lptr[r], en = lptr[r + 1];
    float a0 = 0.f, a1 = 0.f, a2 = 0.f, a3 = 0.f;
    for (int e = s; e < en; e += 8) {
      {
        const int idx = e + slot;
        const int2 q = dst[min(idx, cmax)];
        const float v = (idx < en) ? __int_as_float(q.y) : 0.f;
        const u32 col = (u32)q.x & 0x1FFFFu;
        const uint2 g = *reinterpret_cast<const uint2*>(
            xwb + (size_t)col * DOUT + li * 4);
        a0 = fmaf(v, __uint_as_float(g.x << 16), a0);
        a1 = fmaf(v, __uint_as_float(g.x & 0xFFFF0000u), a1);
        a2 = fmaf(v, __uint_as_float(g.y << 16), a2);
        a3 = fmaf(v, __uint_as_float(g.y & 0xFFFF0000u), a3);
      }
      {
        const int idx = e + 4 + slot;
        const int2 q = dst[min(idx, cmax)];
        const float v = (idx < en) ? __int_as_float(q.y) : 0.f;
        const u32 col = (u32)q.x & 0x1FFFFu;
        const uint2 g = *reinterpret_cast<const uint2*>(
            xwb + (size_t)col * DOUT + li * 4);
        a0 = fmaf(v, __uint_as_float(g.x << 16), a0);
        a1 = fmaf(v, __uint_as_float(g.x & 0xFFFF0000u), a1);
        a2 = fmaf(v, __uint_as_float(g.y << 16), a2);
        a3 = fmaf(v, __uint_as_float(g.y & 0xFFFF0000u), a3);
      }
    }
    // cross-slot reduce: all 4 slot copies of li end up holding the sum
    a0 += __shfl_xor(a0, 16); a0 += __shfl_xor(a0, 32);
    a1 += __shfl_xor(a1, 16); a1 += __shfl_xor(a1, 32);
    a2 += __shfl_xor(a2, 16); a2 += __shfl_xor(a2, 32);
    a3 += __shfl_xor(a3, 16); a3 += __shfl_xor(a3, 32);
    if (slot == 0) {
      float4 o;
      o.x = fmaxf(a0, 0.f); o.y = fmaxf(a1, 0.f);
      o.z = fmaxf(a2, 0.f); o.w = fmaxf(a3, 0.f);
      *reinterpret_cast<float4*>(&out[(size_t)row * DOUT + li * 4]) = o;
    }
  }
}

// ----------------------- fallback (atomic) path ----------------------------
__global__ __launch_bounds__(256) void scatter_kernel(
    const int* __restrict__ erow, const int* __restrict__ ecol,
    const float* __restrict__ eval_, const u16* __restrict__ xwb,
    float* __restrict__ out) {
  const int wave = (blockIdx.x * blockDim.x + threadIdx.x) >> 6;
  const int lane = threadIdx.x & 63;
  const int nwaves = (gridDim.x * blockDim.x) >> 6;
  const int per = (NE + nwaves - 1) / nwaves;
  const int e0 = wave * per;
  const int e1 = min(e0 + per, NE);
  for (int base = e0; base < e1; base += 64) {
    const int e = base + lane;
    int r = 0, c = 0; float v = 0.f;
    if (e < e1) { r = erow[e]; c = ecol[e]; v = eval_[e]; }
    const int cnt = min(64, e1 - base);
    for (int j = 0; j < cnt; ++j) {
      const int rj = __shfl(r, j);
      const int cj = __shfl(c, j);
      const float vj = __shfl(v, j);
      atomicAdd(&out[rj * DOUT + lane], vj * bf2f(xwb[cj * DOUT + lane]));
    }
  }
}

__global__ __launch_bounds__(256) void finish_kernel(float* __restrict__ out) {
  const int idx = (blockIdx.x * blockDim.x + threadIdx.x) * 4;
  if (idx < NN * DOUT) {
    float4 a = *reinterpret_cast<const float4*>(&out[idx]);
    a.x = fmaxf(a.x, 0.f); a.y = fmaxf(a.y, 0.f);
    a.z = fmaxf(a.z, 0.f); a.w = fmaxf(a.w, 0.f);
    *reinterpret_cast<float4*>(&out[idx]) = a;
  }
}

extern "C" void kernel_launch(void* const* d_in, const int* in_sizes, int n_in,
                              void* d_out, int out_size, void* d_ws, size_t ws_size,
                              hipStream_t stream) {
  const float* x     = (const float*)d_in[0];
  const int*   erow  = (const int*)d_in[1];
  const int*   ecol  = (const int*)d_in[2];
  const float* eval_ = (const float*)d_in[3];
  const float* w     = (const float*)d_in[4];
  float* out = (float*)d_out;

  char* ws = (char*)d_ws;
  u16* xwb = (u16*)(ws + XWB_B);
  const bool big_ws = (ws_size >= (size_t)WS_NEED);
  int* gcur = big_ws ? (int*)(ws + GCUR_B) : nullptr;

  const int gemm_grid = (NN + 63) / 64;   // 1563 blocks
  gemm_kernel<<<gemm_grid, 256, 0, stream>>>(x, w, xwb, gcur);

  if (big_ws) {
    int*  gcur64 = (int*)(ws + GCUR64_B);
    int2* bpad   = (int2*)(ws + BPAD_B);
    place5_kernel<<<NBLK, 512, 0, stream>>>(erow, ecol, eval_, gcur, bpad);
    split_kernel<<<NBB, 256, 0, stream>>>(gcur, bpad, gcur64);
    agg3_kernel<<<NB64, 256, 0, stream>>>(gcur64, bpad, xwb, out);
  } else {
    hipMemsetAsync(d_out, 0, (size_t)NN * DOUT * sizeof(float), stream);
    scatter_kernel<<<2048, 256, 0, stream>>>(erow, ecol, eval_, xwb, out);
    const int fin_grid = (NN * DOUT / 4 + 255) / 256;
    finish_kernel<<<fin_grid, 256, 0, stream>>>(out);
  }
}

// Round 13
// 81.396 us; speedup vs baseline: 1.0575x; 1.0575x over previous
//
#include <hip/hip_runtime.h>

#define NN 100000
#define DIN 128
#define DOUT 64
#define NE 1600000

// place granularity (proven): 128-row buckets
#define BSHIFT 7
#define BROWS 128
#define NBB 783              // ceil(100000/128)
#define NBP 1024             // padded key count for place scan
#define CAP 2560             // slots per 128-bucket; mean 2048 -> +11 sigma
#define EPB 4096             // edges per place-block
#define NBLK 391             // ceil(1600000/4096)

// agg granularity (proven): 64-row half-buckets, filtered from parent
#define NB64 1566            // 2 * NBB
#define QRNS 10              // CAP / 256 (parent segment reg cache, exact)
#define CAPQ 1536            // dst capacity per half; mean 1024, +16 sigma

// ---------------- ws layout (bytes) ----------------
#define XWB_B   0u                           // ushort[NN*DOUT] = 12.8 MB
#define GCUR_B  12800000u                    // int[NBB] (padded to 16 KB)
#define BPAD_B  (GCUR_B + 16384u)            // int2[NBB*CAP] = 16.04 MB
#define WS_NEED (BPAD_B + (unsigned)NBB * CAP * 8u)   // ~28.9 MB

typedef unsigned short u16;
typedef unsigned int u32;
typedef __attribute__((ext_vector_type(8))) short v8s;   // 8 bf16 = 4 VGPR
typedef __attribute__((ext_vector_type(4))) float v4f;   // MFMA acc

__device__ __forceinline__ float bf2f(u16 u) {
  return __uint_as_float(((u32)u) << 16);
}
__device__ __forceinline__ u16 f2bf(float f) {
  u32 x = __float_as_uint(f);
  u32 r = x + 0x7fffu + ((x >> 16) & 1u);
  return (u16)(r >> 16);
}

// ---------------------------------------------------------------------------
// GEMM v7 (validated, ~11 us, HBM-bound). Grid 1563 >= NBB=783: one block
// zeroes one gcur slot (stream order guarantees place5 sees zeros).
// ---------------------------------------------------------------------------
__global__ __launch_bounds__(256) void gemm_kernel(
    const float* __restrict__ x, const float* __restrict__ w,
    u16* __restrict__ xwb, int* __restrict__ gz) {
  if (gz != nullptr && threadIdx.x == 0 && blockIdx.x < NBB)
    gz[blockIdx.x] = 0;

  __shared__ u16 wlds[16 * 64 * 8];   // 16 KB
  const int t = threadIdx.x;
  const int lane = t & 63;
  const int wv = t >> 6;

  #pragma unroll
  for (int pi = 0; pi < 4; ++pi) {
    const int p = t * 4 + pi;
    const int f = p >> 6, lp = p & 63;
    const int kc = f >> 2, nc = f & 3;
    const int kg = lp >> 4, lr = lp & 15;
    const int kbase = kc * 32 + kg * 8;
    u32 pk[4];
    #pragma unroll
    for (int h = 0; h < 4; ++h) {
      const u32 lo = f2bf(w[(kbase + 2 * h)     * DOUT + nc * 16 + lr]);
      const u32 hi = f2bf(w[(kbase + 2 * h + 1) * DOUT + nc * 16 + lr]);
      pk[h] = lo | (hi << 16);
    }
    *reinterpret_cast<uint4*>(&wlds[p * 8]) =
        make_uint4(pk[0], pk[1], pk[2], pk[3]);
  }
  __syncthreads();

  const int row0 = blockIdx.x * 64 + wv * 16;
  if (row0 >= NN) return;            // safe: after the only barrier
  const int lrow = lane & 15;
  const int lkg  = lane >> 4;

  v8s Bf[4][4];
  #pragma unroll
  for (int kc = 0; kc < 4; ++kc)
    #pragma unroll
    for (int nc = 0; nc < 4; ++nc)
      Bf[kc][nc] = *reinterpret_cast<const v8s*>(
          &wlds[((kc * 4 + nc) * 64 + lane) * 8]);

  const float* xr = x + (size_t)(row0 + lrow) * DIN + lkg * 8;
  float4 xa[4][2];
  #pragma unroll
  for (int kc = 0; kc < 4; ++kc) {
    xa[kc][0] = *reinterpret_cast<const float4*>(xr + kc * 32);
    xa[kc][1] = *reinterpret_cast<const float4*>(xr + kc * 32 + 4);
  }

  v4f acc[4];
  #pragma unroll
  for (int nc = 0; nc < 4; ++nc) acc[nc] = (v4f){0.f, 0.f, 0.f, 0.f};

  #pragma unroll
  for (int kc = 0; kc < 4; ++kc) {
    v8s Af;
    Af[0] = (short)f2bf(xa[kc][0].x);
    Af[1] = (short)f2bf(xa[kc][0].y);
    Af[2] = (short)f2bf(xa[kc][0].z);
    Af[3] = (short)f2bf(xa[kc][0].w);
    Af[4] = (short)f2bf(xa[kc][1].x);
    Af[5] = (short)f2bf(xa[kc][1].y);
    Af[6] = (short)f2bf(xa[kc][1].z);
    Af[7] = (short)f2bf(xa[kc][1].w);
    #pragma unroll
    for (int nc = 0; nc < 4; ++nc)
      acc[nc] = __builtin_amdgcn_mfma_f32_16x16x32_bf16(Af, Bf[kc][nc],
                                                        acc[nc], 0, 0, 0);
  }

  #pragma unroll
  for (int nc = 0; nc < 4; ++nc)
    #pragma unroll
    for (int j = 0; j < 4; ++j)
      xwb[(size_t)(row0 + lkg * 4 + j) * DOUT + nc * 16 + lrow] =
          f2bf(acc[nc][j]);
}

// ---------------------------------------------------------------------------
// place5 (proven ~21 us, verbatim): EPB=4096 / 512 thr / reg-cached edge
// loads / LDS counting sort / run-contiguous bpad writes, 128-row buckets
// (runs ~5.2 edges). base overlays hist in-place after the scan. LDS 52 KB.
// ---------------------------------------------------------------------------
__global__ __launch_bounds__(512) void place5_kernel(
    const int* __restrict__ erow, const int* __restrict__ ecol,
    const float* __restrict__ eval_, int* __restrict__ gcur,
    int2* __restrict__ bpad) {
  __shared__ int  hist[NBP];       // 4 KB (holds base[] after the claim)
  __shared__ int  lofs[NBP];       // 4 KB
  __shared__ int  lcur[NBP];       // 4 KB
  __shared__ int  wtot[8];
  __shared__ u16  sb[EPB];         // 8 KB   bucket id per sorted pos
  __shared__ int2 dstl[EPB];       // 32 KB  payload per sorted pos

  const int t = threadIdx.x;
  const int lane = t & 63;
  const int wv = t >> 6;
  const int e0 = blockIdx.x * EPB;
  const int e1 = min(e0 + EPB, NE);
  const int ecount = e1 - e0;

  hist[t] = 0;        hist[t + 512] = 0;
  lcur[t] = 0;        lcur[t + 512] = 0;
  __syncthreads();

  // A: histogram; cache all edge data in registers (independent loads)
  int er[8], ec[8];
  float ev[8];
  #pragma unroll
  for (int k = 0; k < 8; ++k) {
    const int e = e0 + t + k * 512;
    if (e < e1) {
      er[k] = erow[e];
      ec[k] = ecol[e];
      ev[k] = eval_[e];
      atomicAdd(&hist[er[k] >> BSHIFT], 1);
    } else {
      er[k] = -1;
    }
  }
  __syncthreads();

  // B: exclusive scan over 1024 keys (pair-per-thread + wave shfl + offsets)
  const int ha = hist[2 * t], hb = hist[2 * t + 1];
  const int ps = ha + hb;
  int s = ps;
  #pragma unroll
  for (int o = 1; o < 64; o <<= 1) {
    const int u = __shfl_up(s, o);
    if (lane >= o) s += u;
  }
  if (lane == 63) wtot[wv] = s;
  __syncthreads();
  int woff = 0;
  #pragma unroll
  for (int w8 = 0; w8 < 8; ++w8) woff += (w8 < wv) ? wtot[w8] : 0;
  const int excl = woff + s - ps;
  lofs[2 * t]     = excl;
  lofs[2 * t + 1] = excl + ha;
  // claim bucket ranges; base overlays hist (owner-thread slots, no race)
  hist[2 * t]     = (ha && 2 * t     < NBB) ? atomicAdd(&gcur[2 * t],     ha) : 0;
  hist[2 * t + 1] = (hb && 2 * t + 1 < NBB) ? atomicAdd(&gcur[2 * t + 1], hb) : 0;
  __syncthreads();

  // C: rank + scatter payload into LDS sorted order (pure LDS)
  #pragma unroll
  for (int k = 0; k < 8; ++k) {
    if (er[k] >= 0) {
      const int b = er[k] >> BSHIFT;
      const int pos = lofs[b] + atomicAdd(&lcur[b], 1);
      dstl[pos] = make_int2(((er[k] & (BROWS - 1)) << 17) | ec[k],
                            __float_as_int(ev[k]));
      sb[pos] = (u16)b;
    }
  }
  __syncthreads();

  // D: stream sorted payload to bpad (runs of ~5.2 edges = contiguous)
  for (int p = t; p < ecount; p += 512) {
    const int b = sb[p];
    const int rk = hist[b] + (p - lofs[b]);   // hist[] holds base now
    if (rk < CAP) bpad[(long)b * CAP + rk] = dstl[p];
  }
}

// ---------------------------------------------------------------------------
// agg9 (round-26): the proven agg3 shape (256 thr / 4 waves / grid ~1566 =
// 6264 waves / reg-cached segment / hist-scan-sort / slot-vectorized gather)
// consuming place5's 128-row layout DIRECTLY: block = one 64-row half;
// reads the parent's full segment into qr[10] (2x read amp, L3-resident)
// and filters by q.x bit 23 during the hist phase. No split kernel, no
// in-place rewrite, no second count array. agg8 proved qr[10] at 256 thr
// compiles clean (36 VGPR, no spill); agg6's 47.9 came from qr[19] crammed
// into 24 VGPR (spill) + 4x amp -- neither applies here.
// ---------------------------------------------------------------------------
__global__ __launch_bounds__(256) void agg9_kernel(
    const int* __restrict__ gcur, const int2* __restrict__ bpad,
    const u16* __restrict__ xwb, float* __restrict__ out) {
  __shared__ int2 dst[CAPQ];       // 12288 B
  __shared__ int  hist[64];
  __shared__ int  lptr[65];
  __shared__ int  cur[64];

  const int bucket64 = blockIdx.x;         // 0..1565
  const int parent = bucket64 >> 1;
  const int half   = bucket64 & 1;
  const int t = threadIdx.x;
  const int count = min(gcur[parent], CAP);
  const long sbase = (long)parent * CAP;

  if (t < 64) hist[t] = 0;
  __syncthreads();

  // read parent segment; keep only our half (filter = 1 AND+cmp per slot)
  int2 qr[QRNS];
  #pragma unroll
  for (int k = 0; k < QRNS; ++k) {
    const int e = t + k * 256;
    qr[k].x = -1;
    if (e < count) {
      const int2 q = bpad[sbase + e];
      if (((q.x >> 23) & 1) == half) {
        qr[k] = q;
        atomicAdd(&hist[(q.x >> 17) & 63], 1);
      }
    }
  }
  __syncthreads();

  if (t < 64) {
    const int v = hist[t];
    int s = v;
    #pragma unroll
    for (int o = 1; o < 64; o <<= 1) {
      const int u = __shfl_up(s, o);
      if (t >= o) s += u;
    }
    lptr[t + 1] = min(s, CAPQ);
    cur[t] = s - v;
    if (t == 0) lptr[0] = 0;
  }
  __syncthreads();

  #pragma unroll
  for (int k = 0; k < QRNS; ++k) {
    if (qr[k].x >= 0) {
      const int r = (qr[k].x >> 17) & 63;
      const int pos = atomicAdd(&cur[r], 1);
      if (pos < CAPQ) dst[pos] = qr[k];
    }
  }
  __syncthreads();

  const int lane = t & 63;
  const int wave = t >> 6;
  const int slot = lane >> 4;      // 0..3  (edge sub-slot)
  const int li   = lane & 15;      // 0..15 (covers 4 cols each via dwordx2)
  const int row0 = bucket64 << 6;
  const int kcount = lptr[64];
  const int cmax = kcount - 1;

  for (int r = wave; r < 64; r += 4) {
    const int row = row0 + r;
    if (row >= NN) break;
    const int s = lptr[r], en = lptr[r + 1];
    float a0 = 0.f, a1 = 0.f, a2 = 0.f, a3 = 0.f;
    for (int e = s; e < en; e += 8) {
      {
        const int idx = e + slot;
        const int2 q = dst[min(idx, cmax)];
        const float v = (idx < en) ? __int_as_float(q.y) : 0.f;
        const u32 col = (u32)q.x & 0x1FFFFu;
        const uint2 g = *reinterpret_cast<const uint2*>(
            xwb + (size_t)col * DOUT + li * 4);
        a0 = fmaf(v, __uint_as_float(g.x << 16), a0);
        a1 = fmaf(v, __uint_as_float(g.x & 0xFFFF0000u), a1);
        a2 = fmaf(v, __uint_as_float(g.y << 16), a2);
        a3 = fmaf(v, __uint_as_float(g.y & 0xFFFF0000u), a3);
      }
      {
        const int idx = e + 4 + slot;
        const int2 q = dst[min(idx, cmax)];
        const float v = (idx < en) ? __int_as_float(q.y) : 0.f;
        const u32 col = (u32)q.x & 0x1FFFFu;
        const uint2 g = *reinterpret_cast<const uint2*>(
            xwb + (size_t)col * DOUT + li * 4);
        a0 = fmaf(v, __uint_as_float(g.x << 16), a0);
        a1 = fmaf(v, __uint_as_float(g.x & 0xFFFF0000u), a1);
        a2 = fmaf(v, __uint_as_float(g.y << 16), a2);
        a3 = fmaf(v, __uint_as_float(g.y & 0xFFFF0000u), a3);
      }
    }
    // cross-slot reduce: all 4 slot copies of li end up holding the sum
    a0 += __shfl_xor(a0, 16); a0 += __shfl_xor(a0, 32);
    a1 += __shfl_xor(a1, 16); a1 += __shfl_xor(a1, 32);
    a2 += __shfl_xor(a2, 16); a2 += __shfl_xor(a2, 32);
    a3 += __shfl_xor(a3, 16); a3 += __shfl_xor(a3, 32);
    if (slot == 0) {
      float4 o;
      o.x = fmaxf(a0, 0.f); o.y = fmaxf(a1, 0.f);
      o.z = fmaxf(a2, 0.f); o.w = fmaxf(a3, 0.f);
      *reinterpret_cast<float4*>(&out[(size_t)row * DOUT + li * 4]) = o;
    }
  }
}

// ----------------------- fallback (atomic) path ----------------------------
__global__ __launch_bounds__(256) void scatter_kernel(
    const int* __restrict__ erow, const int* __restrict__ ecol,
    const float* __restrict__ eval_, const u16* __restrict__ xwb,
    float* __restrict__ out) {
  const int wave = (blockIdx.x * blockDim.x + threadIdx.x) >> 6;
  const int lane = threadIdx.x & 63;
  const int nwaves = (gridDim.x * blockDim.x) >> 6;
  const int per = (NE + nwaves - 1) / nwaves;
  const int e0 = wave * per;
  const int e1 = min(e0 + per, NE);
  for (int base = e0; base < e1; base += 64) {
    const int e = base + lane;
    int r = 0, c = 0; float v = 0.f;
    if (e < e1) { r = erow[e]; c = ecol[e]; v = eval_[e]; }
    const int cnt = min(64, e1 - base);
    for (int j = 0; j < cnt; ++j) {
      const int rj = __shfl(r, j);
      const int cj = __shfl(c, j);
      const float vj = __shfl(v, j);
      atomicAdd(&out[rj * DOUT + lane], vj * bf2f(xwb[cj * DOUT + lane]));
    }
  }
}

__global__ __launch_bounds__(256) void finish_kernel(float* __restrict__ out) {
  const int idx = (blockIdx.x * blockDim.x + threadIdx.x) * 4;
  if (idx < NN * DOUT) {
    float4 a = *reinterpret_cast<const float4*>(&out[idx]);
    a.x = fmaxf(a.x, 0.f); a.y = fmaxf(a.y, 0.f);
    a.z = fmaxf(a.z, 0.f); a.w = fmaxf(a.w, 0.f);
    *reinterpret_cast<float4*>(&out[idx]) = a;
  }
}

extern "C" void kernel_launch(void* const* d_in, const int* in_sizes, int n_in,
                              void* d_out, int out_size, void* d_ws, size_t ws_size,
                              hipStream_t stream) {
  const float* x     = (const float*)d_in[0];
  const int*   erow  = (const int*)d_in[1];
  const int*   ecol  = (const int*)d_in[2];
  const float* eval_ = (const float*)d_in[3];
  const float* w     = (const float*)d_in[4];
  float* out = (float*)d_out;

  char* ws = (char*)d_ws;
  u16* xwb = (u16*)(ws + XWB_B);
  const bool big_ws = (ws_size >= (size_t)WS_NEED);
  int* gcur = big_ws ? (int*)(ws + GCUR_B) : nullptr;

  const int gemm_grid = (NN + 63) / 64;   // 1563 blocks
  gemm_kernel<<<gemm_grid, 256, 0, stream>>>(x, w, xwb, gcur);

  if (big_ws) {
    int2* bpad = (int2*)(ws + BPAD_B);
    place5_kernel<<<NBLK, 512, 0, stream>>>(erow, ecol, eval_, gcur, bpad);
    agg9_kernel<<<NB64, 256, 0, stream>>>(gcur, bpad, xwb, out);
  } else {
    hipMemsetAsync(d_out, 0, (size_t)NN * DOUT * sizeof(float), stream);
    scatter_kernel<<<2048, 256, 0, stream>>>(erow, ecol, eval_, xwb, out);
    const int fin_grid = (NN * DOUT / 4 + 255) / 256;
    finish_kernel<<<fin_grid, 256, 0, stream>>>(out);
  }
}